// Round 3
// 6352.971 us; speedup vs baseline: 1.4889x; 1.4889x over previous
//
#include <hip/hip_runtime.h>
#include <math.h>

// Problem constants (Encoder, D=768, H=12, L=12)
#define BB 4
#define TT 1024
#define DD 768
#define HH 12
#define DH 64
#define FF2 3072
#define NL 12
#define MM (BB * TT)            // 4096 rows
#define SCALE 0.03608439182435161f   // 768^-0.5
#define LN_EPS 1e-5f

typedef __attribute__((ext_vector_type(8))) short bf16x8;
typedef __attribute__((ext_vector_type(4))) float f32x4;

__device__ __forceinline__ ushort f2b(float x) {   // fp32 -> bf16 RNE
    uint u = __float_as_uint(x);
    uint r = (u + 0x7fffu + ((u >> 16) & 1u)) >> 16;
    return (ushort)r;
}
__device__ __forceinline__ float b2f(ushort h) { return __uint_as_float(((uint)h) << 16); }

__device__ __forceinline__ float gelu_exact(float x) {
    return 0.5f * x * (1.0f + erff(x * 0.70710678118654752440f));
}

// XOR-swizzled 16B-chunk index for a [rows][32] bf16 tile:
// data (row r, k-chunk q of 8 bf16) lives at chunk 4r + (q ^ (r&3) ^ ((r>>2)&3)).
__device__ __forceinline__ int swz(int r, int q) {
    return 4 * r + ((q ^ (r & 3) ^ ((r >> 2) & 3)) & 3);
}

// ---------------------------------------------------------------------------
// LayerNorm: one block per row of 768, 256 threads; bf16 output
// ---------------------------------------------------------------------------
__global__ __launch_bounds__(256) void ln_kernel(const float* __restrict__ x,
                                                 const float* __restrict__ g,
                                                 const float* __restrict__ b,
                                                 ushort* __restrict__ out) {
    const int r = blockIdx.x;
    const int tid = threadIdx.x;
    const float* xr = x + (size_t)r * DD;
    float v0 = xr[tid], v1 = xr[tid + 256], v2 = xr[tid + 512];

    __shared__ float red[256];
    red[tid] = v0 + v1 + v2;
    __syncthreads();
    for (int off = 128; off > 0; off >>= 1) {
        if (tid < off) red[tid] += red[tid + off];
        __syncthreads();
    }
    float mu = red[0] * (1.0f / DD);
    __syncthreads();

    float d0 = v0 - mu, d1 = v1 - mu, d2 = v2 - mu;
    red[tid] = d0 * d0 + d1 * d1 + d2 * d2;
    __syncthreads();
    for (int off = 128; off > 0; off >>= 1) {
        if (tid < off) red[tid] += red[tid + off];
        __syncthreads();
    }
    float rstd = rsqrtf(red[0] * (1.0f / DD) + LN_EPS);

    ushort* outr = out + (size_t)r * DD;
    outr[tid]       = f2b(d0 * rstd * g[tid]       + b[tid]);
    outr[tid + 256] = f2b(d1 * rstd * g[tid + 256] + b[tid + 256]);
    outr[tid + 512] = f2b(d2 * rstd * g[tid + 512] + b[tid + 512]);
}

// ---------------------------------------------------------------------------
// Transpose + fp32->bf16 convert: W[R][C] -> Wt[C][R].  block (32,8)
// ---------------------------------------------------------------------------
__global__ __launch_bounds__(256) void tconv(const float* __restrict__ W,
                                             ushort* __restrict__ Wt,
                                             int R, int C) {
    __shared__ float t[32][33];
    const int tx = threadIdx.x, ty = threadIdx.y;
    const int gr = blockIdx.y * 32, gc = blockIdx.x * 32;
#pragma unroll
    for (int i = 0; i < 4; ++i)
        t[ty + 8 * i][tx] = W[(size_t)(gr + ty + 8 * i) * C + gc + tx];
    __syncthreads();
#pragma unroll
    for (int i = 0; i < 4; ++i)
        Wt[(size_t)(gc + ty + 8 * i) * R + gr + tx] = f2b(t[tx][ty + 8 * i]);
}

// ---------------------------------------------------------------------------
// bf16 transpose: V[b][t][h*64+d] -> Vt[(b*H+h)][d][t].  block (32,8)
// grid (TT/32, DH/32, BB*HH)
// ---------------------------------------------------------------------------
__global__ __launch_bounds__(256) void vtrans(const ushort* __restrict__ V,
                                              ushort* __restrict__ Vt) {
    __shared__ ushort t[32][34];
    const int tx = threadIdx.x, ty = threadIdx.y;
    const int t0 = blockIdx.x * 32;
    const int d0 = blockIdx.y * 32;
    const int bh = blockIdx.z;
    const int b = bh / HH, h = bh % HH;
    const ushort* src = V + ((size_t)(b * TT + t0)) * DD + h * DH + d0;
#pragma unroll
    for (int i = 0; i < 4; ++i)
        t[ty + 8 * i][tx] = src[(size_t)(ty + 8 * i) * DD + tx];
    __syncthreads();
    ushort* dst = Vt + ((size_t)bh * DH + d0) * TT + t0;
#pragma unroll
    for (int i = 0; i < 4; ++i)
        dst[(size_t)(ty + 8 * i) * TT + tx] = t[tx][ty + 8 * i];
}

// ---------------------------------------------------------------------------
// MFMA bf16 GEMM: C[M,N] = epi(A[M,K] @ Wt[N,K]^T + bias[N] (+ res fp32))
// ---------------------------------------------------------------------------
template <int BN, int EPI, bool OBF16>
__global__ __launch_bounds__(256) void mfma_gemm(const ushort* __restrict__ A,
                                                 const ushort* __restrict__ Wt,
                                                 const float* __restrict__ bias,
                                                 const float* __restrict__ res,
                                                 void* __restrict__ Cout,
                                                 int M, int N, int K) {
    constexpr int BM = 128;
    constexpr int ACH = BM * 4;             // 16B chunks in A tile
    constexpr int BCH = BN * 4;
    constexpr int PT = (ACH + BCH) / 256;   // chunks per thread
    constexpr int NI = (BN == 128) ? 4 : 2;
    constexpr int NJ = 4;

    __shared__ ushort As[BM * 32];
    __shared__ ushort Bs[BN * 32];

    const int tid = threadIdx.x;
    const int lane = tid & 63, wave = tid >> 6;
    const int wm = (BN == 128) ? (wave & 1) * 64 : wave * 32;
    const int wn = (BN == 128) ? (wave >> 1) * 64 : 0;
    const int m0 = blockIdx.y * BM, n0 = blockIdx.x * BN;

    f32x4 acc[NI][NJ];
#pragma unroll
    for (int i = 0; i < NI; ++i)
#pragma unroll
        for (int j = 0; j < NJ; ++j) acc[i][j] = (f32x4){0.f, 0.f, 0.f, 0.f};

    const ushort* gsrc[PT];
    ushort* ldst[PT];
#pragma unroll
    for (int s = 0; s < PT; ++s) {
        int c = tid + 256 * s;
        if (c < ACH) {
            int r = c >> 2, qs = c & 3;
            int ql = qs ^ (r & 3) ^ ((r >> 2) & 3);
            gsrc[s] = A + (size_t)(m0 + r) * K + ql * 8;
            ldst[s] = As + c * 8;
        } else {
            int cb = c - ACH;
            int r = cb >> 2, qs = cb & 3;
            int ql = qs ^ (r & 3) ^ ((r >> 2) & 3);
            gsrc[s] = Wt + (size_t)(n0 + r) * K + ql * 8;
            ldst[s] = Bs + cb * 8;
        }
    }

    const int q = lane >> 4;
    int ca[NI], cb[NJ];
#pragma unroll
    for (int i = 0; i < NI; ++i) { int r = wm + i * 16 + (lane & 15); ca[i] = swz(r, q); }
#pragma unroll
    for (int j = 0; j < NJ; ++j) { int r = wn + j * 16 + (lane & 15); cb[j] = swz(r, q); }

    for (int k0 = 0; k0 < K; k0 += 32) {
        uint4 tmp[PT];
#pragma unroll
        for (int s = 0; s < PT; ++s) tmp[s] = *(const uint4*)(gsrc[s] + k0);
        __syncthreads();
#pragma unroll
        for (int s = 0; s < PT; ++s) *(uint4*)(ldst[s]) = tmp[s];
        __syncthreads();

        bf16x8 af[NI], bfr[NJ];
#pragma unroll
        for (int i = 0; i < NI; ++i) af[i] = *(const bf16x8*)(As + ca[i] * 8);
#pragma unroll
        for (int j = 0; j < NJ; ++j) bfr[j] = *(const bf16x8*)(Bs + cb[j] * 8);
#pragma unroll
        for (int i = 0; i < NI; ++i)
#pragma unroll
            for (int j = 0; j < NJ; ++j)
                acc[i][j] = __builtin_amdgcn_mfma_f32_16x16x32_bf16(af[i], bfr[j], acc[i][j], 0, 0, 0);
    }

    const int col = lane & 15, rq = (lane >> 4) * 4;
#pragma unroll
    for (int j = 0; j < NJ; ++j) {
        const int n = n0 + wn + j * 16 + col;
        const float bj = bias[n];
#pragma unroll
        for (int i = 0; i < NI; ++i) {
#pragma unroll
            for (int r4 = 0; r4 < 4; ++r4) {
                const int m = m0 + wm + i * 16 + rq + r4;
                float v = acc[i][j][r4] + bj;
                if (EPI == 1) v += res[(size_t)m * N + n];
                if (EPI == 2) v = gelu_exact(v);
                if (OBF16) ((ushort*)Cout)[(size_t)m * N + n] = f2b(v);
                else       ((float*)Cout)[(size_t)m * N + n] = v;
            }
        }
    }
}

// ---------------------------------------------------------------------------
// MFMA flash attention (quirky: scores = q . v).  bf16 Q/V in, bf16 ctx out.
// One block per (b, h, 128-query tile); 4 waves, each owns 32 queries.
// ---------------------------------------------------------------------------
__global__ __launch_bounds__(256) void attn_mfma(const ushort* __restrict__ Q,
                                                 const ushort* __restrict__ V,
                                                 const ushort* __restrict__ Vt,
                                                 ushort* __restrict__ Ctx) {
    const int qt = blockIdx.x & 7;            // TT/128 = 8 q-tiles
    const int h  = (blockIdx.x >> 3) % HH;
    const int b  = blockIdx.x / (8 * HH);
    const int tid = threadIdx.x;
    const int lane = tid & 63, wave = tid >> 6;
    const int l15 = lane & 15, lq = lane >> 4;

    // 72-element row stride (144B): b128 fragment reads hit the structural
    // bank minimum (a 128B stride would be a 16-way conflict).
    __shared__ __align__(16) ushort Vs [64][72];    // V tile  [t][d]
    __shared__ __align__(16) ushort Vts[64][72];    // V^T tile [d][t]
    __shared__ __align__(16) ushort Ps [128][72];   // P tile  [q][t], wave-private rows

    const int q0 = qt * 128;
    const int wq = wave * 32;

    // Q fragments (32 q rows x 64 d) live in registers for the whole kernel
    bf16x8 qf[2][2];
    const ushort* Qb = Q + ((size_t)(b * TT + q0 + wq)) * DD + h * DH;
#pragma unroll
    for (int i = 0; i < 2; ++i)
#pragma unroll
        for (int ks = 0; ks < 2; ++ks)
            qf[i][ks] = *(const bf16x8*)(Qb + (size_t)(16 * i + l15) * DD + 32 * ks + lq * 8);

    const ushort* Vb  = V  + ((size_t)b * TT) * DD + h * DH;
    const ushort* Vtb = Vt + ((size_t)(b * HH + h) * DH) * TT;

    f32x4 O[2][4];
    float lsum[2][4];
#pragma unroll
    for (int i = 0; i < 2; ++i)
#pragma unroll
        for (int j = 0; j < 4; ++j) O[i][j] = (f32x4){0.f, 0.f, 0.f, 0.f};
#pragma unroll
    for (int i = 0; i < 2; ++i)
#pragma unroll
        for (int r = 0; r < 4; ++r) lsum[i][r] = 0.f;

    for (int t = 0; t < 16; ++t) {
        const int t0 = t * 64;
        uint4 va[2], vta[2];
#pragma unroll
        for (int c = 0; c < 2; ++c) {
            int idx = tid + 256 * c;
            int r = idx >> 3, q8 = idx & 7;
            va[c]  = *(const uint4*)(Vb  + (size_t)(t0 + r) * DD + q8 * 8);
            vta[c] = *(const uint4*)(Vtb + (size_t)r * TT + t0 + q8 * 8);
        }
        __syncthreads();                 // previous iter's fragment reads done
#pragma unroll
        for (int c = 0; c < 2; ++c) {
            int idx = tid + 256 * c;
            int r = idx >> 3, q8 = idx & 7;
            *(uint4*)(&Vs[r][q8 * 8])  = va[c];
            *(uint4*)(&Vts[r][q8 * 8]) = vta[c];
        }
        __syncthreads();                 // tiles ready

        // ---- S = Q . V over d (quirky attention: V plays the key role) ----
        f32x4 s[2][4];
#pragma unroll
        for (int i = 0; i < 2; ++i)
#pragma unroll
            for (int j = 0; j < 4; ++j) s[i][j] = (f32x4){0.f, 0.f, 0.f, 0.f};
#pragma unroll
        for (int ks = 0; ks < 2; ++ks)
#pragma unroll
            for (int j = 0; j < 4; ++j) {
                bf16x8 vf = *(const bf16x8*)(&Vs[16 * j + l15][32 * ks + lq * 8]);
                s[0][j] = __builtin_amdgcn_mfma_f32_16x16x32_bf16(qf[0][ks], vf, s[0][j], 0, 0, 0);
                s[1][j] = __builtin_amdgcn_mfma_f32_16x16x32_bf16(qf[1][ks], vf, s[1][j], 0, 0, 0);
            }

        // ---- P = exp(S*SCALE) rounded to bf16; lsum sums the rounded values
        // so the final normalization matches what PV actually accumulates.
#pragma unroll
        for (int i = 0; i < 2; ++i)
#pragma unroll
            for (int j = 0; j < 4; ++j)
#pragma unroll
                for (int r = 0; r < 4; ++r) {
                    float p = __expf(s[i][j][r] * SCALE);
                    ushort pb = f2b(p);
                    lsum[i][r] += b2f(pb);
                    Ps[wq + 16 * i + lq * 4 + r][16 * j + l15] = pb;
                }
        // wave-private Ps rows: same-wave LDS write->read needs no barrier

        // ---- O += P @ V ----
#pragma unroll
        for (int ks = 0; ks < 2; ++ks) {
            bf16x8 pf0 = *(const bf16x8*)(&Ps[wq + l15][32 * ks + lq * 8]);
            bf16x8 pf1 = *(const bf16x8*)(&Ps[wq + 16 + l15][32 * ks + lq * 8]);
#pragma unroll
            for (int jd = 0; jd < 4; ++jd) {
                bf16x8 vtf = *(const bf16x8*)(&Vts[16 * jd + l15][32 * ks + lq * 8]);
                O[0][jd] = __builtin_amdgcn_mfma_f32_16x16x32_bf16(pf0, vtf, O[0][jd], 0, 0, 0);
                O[1][jd] = __builtin_amdgcn_mfma_f32_16x16x32_bf16(pf1, vtf, O[1][jd], 0, 0, 0);
            }
        }
    }

    // ---- reduce lsum across the 16 lanes sharing the same q rows ----
#pragma unroll
    for (int i = 0; i < 2; ++i)
#pragma unroll
        for (int r = 0; r < 4; ++r) {
            float l = lsum[i][r];
            l += __shfl_xor(l, 1);
            l += __shfl_xor(l, 2);
            l += __shfl_xor(l, 4);
            l += __shfl_xor(l, 8);
            lsum[i][r] = 1.0f / l;
        }

    // ---- normalize + write bf16 ctx ----
    ushort* Cb = Ctx + ((size_t)(b * TT + q0 + wq)) * DD + h * DH;
#pragma unroll
    for (int i = 0; i < 2; ++i)
#pragma unroll
        for (int r = 0; r < 4; ++r) {
            const int row = 16 * i + lq * 4 + r;
            const float inv = lsum[i][r];
#pragma unroll
            for (int jd = 0; jd < 4; ++jd)
                Cb[(size_t)row * DD + 16 * jd + l15] = f2b(O[i][jd][r] * inv);
        }
}

// ---------------------------------------------------------------------------
// Host launch
// ---------------------------------------------------------------------------
extern "C" void kernel_launch(void* const* d_in, const int* in_sizes, int n_in,
                              void* d_out, int out_size, void* d_ws, size_t ws_size,
                              hipStream_t stream) {
    const float* x_in  = (const float*)d_in[0];
    const float* ln1_g = (const float*)d_in[1];
    const float* ln1_b = (const float*)d_in[2];
    const float* Wq    = (const float*)d_in[3];
    const float* bq    = (const float*)d_in[4];
    const float* Wv    = (const float*)d_in[5];
    const float* bv    = (const float*)d_in[6];
    const float* Wo    = (const float*)d_in[7];
    const float* bo    = (const float*)d_in[8];
    const float* ln2_g = (const float*)d_in[9];
    const float* ln2_b = (const float*)d_in[10];
    const float* W1    = (const float*)d_in[11];
    const float* b1    = (const float*)d_in[12];
    const float* W2    = (const float*)d_in[13];
    const float* b2    = (const float*)d_in[14];

    float* x = (float*)d_out;                 // residual stream (fp32)
    ushort* h   = (ushort*)d_ws;              // M*D bf16 (ln1 out; reused as Vt)
    ushort* qb  = h   + (size_t)MM * DD;
    ushort* vb  = qb  + (size_t)MM * DD;
    ushort* ctx = vb  + (size_t)MM * DD;
    ushort* h2  = ctx + (size_t)MM * DD;
    ushort* a1  = h2  + (size_t)MM * DD;      // M*FF bf16
    ushort* Wtq = a1  + (size_t)MM * FF2;
    ushort* Wtv = Wtq + (size_t)DD * DD;
    ushort* Wto = Wtv + (size_t)DD * DD;
    ushort* Wt1 = Wto + (size_t)DD * DD;      // [FF][D]
    ushort* Wt2 = Wt1 + (size_t)DD * FF2;     // [D][FF]
    ushort* vt  = h;   // V^T [(b*H+h)][d][t]; h is dead after the q/v GEMMs

    hipMemcpyAsync(x, x_in, (size_t)MM * DD * sizeof(float),
                   hipMemcpyDeviceToDevice, stream);

    const dim3 blk(256);
    const dim3 t32(32, 8);
    const dim3 gD(12, 32);    // N=768, BN=64
    const dim3 gF(24, 32);    // N=3072, BN=128

    for (int l = 0; l < NL; ++l) {
        const float* Wq_l = Wq + (size_t)l * DD * DD;
        const float* Wv_l = Wv + (size_t)l * DD * DD;
        const float* Wo_l = Wo + (size_t)l * DD * DD;
        const float* W1_l = W1 + (size_t)l * DD * FF2;
        const float* W2_l = W2 + (size_t)l * FF2 * DD;

        tconv<<<dim3(24, 24), t32, 0, stream>>>(Wq_l, Wtq, DD, DD);
        tconv<<<dim3(24, 24), t32, 0, stream>>>(Wv_l, Wtv, DD, DD);
        tconv<<<dim3(24, 24), t32, 0, stream>>>(Wo_l, Wto, DD, DD);
        tconv<<<dim3(96, 24), t32, 0, stream>>>(W1_l, Wt1, DD, FF2);
        tconv<<<dim3(24, 96), t32, 0, stream>>>(W2_l, Wt2, FF2, DD);

        ln_kernel<<<MM, blk, 0, stream>>>(x, ln1_g + l * DD, ln1_b + l * DD, h);

        mfma_gemm<64, 0, true><<<gD, blk, 0, stream>>>(h, Wtq, bq + l * DD, nullptr, qb, MM, DD, DD);
        mfma_gemm<64, 0, true><<<gD, blk, 0, stream>>>(h, Wtv, bv + l * DD, nullptr, vb, MM, DD, DD);

        // V^T for the PV mfma B-operand (aliases h, which is now dead)
        vtrans<<<dim3(TT / 32, DH / 32, BB * HH), t32, 0, stream>>>(vb, vt);

        attn_mfma<<<BB * HH * (TT / 128), blk, 0, stream>>>(qb, vb, vt, ctx);

        // x = x + ctx @ Wo + bo (fp32 residual)
        mfma_gemm<64, 1, false><<<gD, blk, 0, stream>>>(ctx, Wto, bo + l * DD, x, x, MM, DD, DD);

        ln_kernel<<<MM, blk, 0, stream>>>(x, ln2_g + l * DD, ln2_b + l * DD, h2);

        // a1 = gelu(h2 @ W1 + b1)
        mfma_gemm<128, 2, true><<<gF, blk, 0, stream>>>(h2, Wt1, b1 + l * FF2, nullptr, a1, MM, FF2, DD);

        // x = x + a1 @ W2 + b2
        mfma_gemm<64, 1, false><<<gD, blk, 0, stream>>>(a1, Wt2, b2 + l * DD, x, x, MM, DD, FF2);
    }
}

// Round 4
// 3024.730 us; speedup vs baseline: 3.1272x; 2.1003x over previous
//
#include <hip/hip_runtime.h>
#include <math.h>

// Problem constants (Encoder, D=768, H=12, L=12)
#define BB 4
#define TT 1024
#define DD 768
#define HH 12
#define DH 64
#define FF2 3072
#define NL 12
#define MM (BB * TT)            // 4096 rows
#define SCALE 0.03608439182435161f   // 768^-0.5
#define LN_EPS 1e-5f

typedef __attribute__((ext_vector_type(8))) short bf16x8;
typedef __attribute__((ext_vector_type(4))) float f32x4;

__device__ __forceinline__ ushort f2b(float x) {   // fp32 -> bf16 RNE
    uint u = __float_as_uint(x);
    uint r = (u + 0x7fffu + ((u >> 16) & 1u)) >> 16;
    return (ushort)r;
}
__device__ __forceinline__ float b2f(ushort h) { return __uint_as_float(((uint)h) << 16); }

__device__ __forceinline__ float gelu_exact(float x) {
    return 0.5f * x * (1.0f + erff(x * 0.70710678118654752440f));
}

// XOR-swizzled 16B-chunk index for a [rows][32] bf16 tile:
// data (row r, k-chunk q of 8 bf16) lives at chunk 4r + (q ^ (r&3) ^ ((r>>2)&3)).
__device__ __forceinline__ int swz(int r, int q) {
    return 4 * r + ((q ^ (r & 3) ^ ((r >> 2) & 3)) & 3);
}

// async 16B global -> LDS DMA (dest must be wave-uniform base + lane*16)
__device__ __forceinline__ void gl_lds16(const ushort* g, ushort* l) {
    __builtin_amdgcn_global_load_lds(
        (__attribute__((address_space(1))) void*)(g),
        (__attribute__((address_space(3))) void*)(l), 16, 0, 0);
}

// ---------------------------------------------------------------------------
// LayerNorm: one block per row of 768, 256 threads; bf16 output
// ---------------------------------------------------------------------------
__global__ __launch_bounds__(256) void ln_kernel(const float* __restrict__ x,
                                                 const float* __restrict__ g,
                                                 const float* __restrict__ b,
                                                 ushort* __restrict__ out) {
    const int r = blockIdx.x;
    const int tid = threadIdx.x;
    const float* xr = x + (size_t)r * DD;
    float v0 = xr[tid], v1 = xr[tid + 256], v2 = xr[tid + 512];

    __shared__ float red[256];
    red[tid] = v0 + v1 + v2;
    __syncthreads();
    for (int off = 128; off > 0; off >>= 1) {
        if (tid < off) red[tid] += red[tid + off];
        __syncthreads();
    }
    float mu = red[0] * (1.0f / DD);
    __syncthreads();

    float d0 = v0 - mu, d1 = v1 - mu, d2 = v2 - mu;
    red[tid] = d0 * d0 + d1 * d1 + d2 * d2;
    __syncthreads();
    for (int off = 128; off > 0; off >>= 1) {
        if (tid < off) red[tid] += red[tid + off];
        __syncthreads();
    }
    float rstd = rsqrtf(red[0] * (1.0f / DD) + LN_EPS);

    ushort* outr = out + (size_t)r * DD;
    outr[tid]       = f2b(d0 * rstd * g[tid]       + b[tid]);
    outr[tid + 256] = f2b(d1 * rstd * g[tid + 256] + b[tid + 256]);
    outr[tid + 512] = f2b(d2 * rstd * g[tid + 512] + b[tid + 512]);
}

// ---------------------------------------------------------------------------
// Transpose + fp32->bf16 convert: W[R][C] -> Wt[C][R].  block (32,8)
// ---------------------------------------------------------------------------
__global__ __launch_bounds__(256) void tconv(const float* __restrict__ W,
                                             ushort* __restrict__ Wt,
                                             int R, int C) {
    __shared__ float t[32][33];
    const int tx = threadIdx.x, ty = threadIdx.y;
    const int gr = blockIdx.y * 32, gc = blockIdx.x * 32;
#pragma unroll
    for (int i = 0; i < 4; ++i)
        t[ty + 8 * i][tx] = W[(size_t)(gr + ty + 8 * i) * C + gc + tx];
    __syncthreads();
#pragma unroll
    for (int i = 0; i < 4; ++i)
        Wt[(size_t)(gc + ty + 8 * i) * R + gr + tx] = f2b(t[tx][ty + 8 * i]);
}

// ---------------------------------------------------------------------------
// bf16 transpose: V[b][t][h*64+d] -> Vt[(b*H+h)][d][t].  block (32,8)
// grid (TT/32, DH/32, BB*HH)
// ---------------------------------------------------------------------------
__global__ __launch_bounds__(256) void vtrans(const ushort* __restrict__ V,
                                              ushort* __restrict__ Vt) {
    __shared__ ushort t[32][34];
    const int tx = threadIdx.x, ty = threadIdx.y;
    const int t0 = blockIdx.x * 32;
    const int d0 = blockIdx.y * 32;
    const int bh = blockIdx.z;
    const int b = bh / HH, h = bh % HH;
    const ushort* src = V + ((size_t)(b * TT + t0)) * DD + h * DH + d0;
#pragma unroll
    for (int i = 0; i < 4; ++i)
        t[ty + 8 * i][tx] = src[(size_t)(ty + 8 * i) * DD + tx];
    __syncthreads();
    ushort* dst = Vt + ((size_t)bh * DH + d0) * TT + t0;
#pragma unroll
    for (int i = 0; i < 4; ++i)
        dst[(size_t)(ty + 8 * i) * TT + tx] = t[tx][ty + 8 * i];
}

// ---------------------------------------------------------------------------
// MFMA bf16 GEMM: C[M,N] = epi(A[M,K] @ Wt[N,K]^T + bias[N] (+ res fp32))
// Pipelined: global_load_lds (16B) DMA, triple-buffered LDS, prefetch depth 2,
// one raw s_barrier per K-step with counted vmcnt (never 0 mid-loop).
// ---------------------------------------------------------------------------
template <int BN, int EPI, bool OBF16>
__global__ __launch_bounds__(256) void mfma_gemm(const ushort* __restrict__ A,
                                                 const ushort* __restrict__ Wt,
                                                 const float* __restrict__ bias,
                                                 const float* __restrict__ res,
                                                 void* __restrict__ Cout,
                                                 int M, int N, int K) {
    constexpr int BM = 128;
    constexpr int ACH = BM * 4;             // 16B chunks in A tile (=512)
    constexpr int BCH = BN * 4;
    constexpr int CH  = ACH + BCH;          // chunks per K-step tile
    constexpr int PT  = CH / 256;           // DMA chunks per thread (3 or 4)
    constexpr int NI = (BN == 128) ? 4 : 2;
    constexpr int NJ = 4;

    // combined A|B tile, 3 buffers: A chunks [0,ACH), B chunks [ACH,CH)
    __shared__ __align__(16) ushort Tile[3][CH * 8];

    const int tid = threadIdx.x;
    const int lane = tid & 63, wave = tid >> 6;
    const int wm = (BN == 128) ? (wave & 1) * 64 : wave * 32;
    const int wn = (BN == 128) ? (wave >> 1) * 64 : 0;
    const int m0 = blockIdx.y * BM, n0 = blockIdx.x * BN;

    f32x4 acc[NI][NJ];
#pragma unroll
    for (int i = 0; i < NI; ++i)
#pragma unroll
        for (int j = 0; j < NJ; ++j) acc[i][j] = (f32x4){0.f, 0.f, 0.f, 0.f};

    // per-thread DMA source pointers (pre-swizzled global chunk; linear LDS dest)
    const ushort* gsrc[PT];
#pragma unroll
    for (int s = 0; s < PT; ++s) {
        int c = tid + 256 * s;
        if (c < ACH) {
            int r = c >> 2, qs = c & 3;
            int ql = qs ^ (r & 3) ^ ((r >> 2) & 3);
            gsrc[s] = A + (size_t)(m0 + r) * K + ql * 8;
        } else {
            int cb = c - ACH;
            int r = cb >> 2, qs = cb & 3;
            int ql = qs ^ (r & 3) ^ ((r >> 2) & 3);
            gsrc[s] = Wt + (size_t)(n0 + r) * K + ql * 8;
        }
    }

    auto stage = [&](int bi, int k0) {
#pragma unroll
        for (int s = 0; s < PT; ++s)
            gl_lds16(gsrc[s] + k0, &Tile[bi][(tid + 256 * s) * 8]);
    };

    // per-lane fragment LDS chunk indices (within a buffer)
    const int q = lane >> 4;
    int ca[NI], cb[NJ];
#pragma unroll
    for (int i = 0; i < NI; ++i) { int r = wm + i * 16 + (lane & 15); ca[i] = swz(r, q); }
#pragma unroll
    for (int j = 0; j < NJ; ++j) { int r = wn + j * 16 + (lane & 15); cb[j] = ACH + swz(r, q); }

    const int NT = K / 32;
    stage(0, 0);
    stage(1, 32);

    for (int t = 0; t < NT; ++t) {
        // my DMA for tile t arrived (FIFO: oldest retire first); my ds_reads
        // from the previous step are complete (so the rotated buffer is safe
        // to overwrite after the barrier).
        if (t < NT - 1) {
            if constexpr (PT == 3) asm volatile("s_waitcnt vmcnt(3) lgkmcnt(0)" ::: "memory");
            else                   asm volatile("s_waitcnt vmcnt(4) lgkmcnt(0)" ::: "memory");
        } else {
            asm volatile("s_waitcnt vmcnt(0) lgkmcnt(0)" ::: "memory");
        }
        __builtin_amdgcn_s_barrier();     // tile t visible to all; all readers past t-1

        if (t + 2 < NT) stage((t + 2) % 3, (t + 2) * 32);   // prefetch depth 2

        const int bi = t % 3;
        bf16x8 af[NI], bfr[NJ];
#pragma unroll
        for (int i = 0; i < NI; ++i) af[i] = *(const bf16x8*)(&Tile[bi][ca[i] * 8]);
#pragma unroll
        for (int j = 0; j < NJ; ++j) bfr[j] = *(const bf16x8*)(&Tile[bi][cb[j] * 8]);
#pragma unroll
        for (int i = 0; i < NI; ++i)
#pragma unroll
            for (int j = 0; j < NJ; ++j)
                acc[i][j] = __builtin_amdgcn_mfma_f32_16x16x32_bf16(af[i], bfr[j], acc[i][j], 0, 0, 0);
    }

    // epilogue: D col = lane&15, row = (lane>>4)*4 + reg
    const int col = lane & 15, rq = (lane >> 4) * 4;
#pragma unroll
    for (int j = 0; j < NJ; ++j) {
        const int n = n0 + wn + j * 16 + col;
        const float bj = bias[n];
#pragma unroll
        for (int i = 0; i < NI; ++i) {
#pragma unroll
            for (int r4 = 0; r4 < 4; ++r4) {
                const int m = m0 + wm + i * 16 + rq + r4;
                float v = acc[i][j][r4] + bj;
                if (EPI == 1) v += res[(size_t)m * N + n];
                if (EPI == 2) v = gelu_exact(v);
                if (OBF16) ((ushort*)Cout)[(size_t)m * N + n] = f2b(v);
                else       ((float*)Cout)[(size_t)m * N + n] = v;
            }
        }
    }
}

// ---------------------------------------------------------------------------
// MFMA flash attention (quirky: scores = q . v).  bf16 Q/V in, bf16 ctx out.
// One block per (b, h, 128-query tile); 4 waves, each owns 32 queries.
// Next tile's V/Vt register loads are issued before the compute phase so
// their latency hides under the 32 MFMAs + 32 exps.
// ---------------------------------------------------------------------------
__global__ __launch_bounds__(256) void attn_mfma(const ushort* __restrict__ Q,
                                                 const ushort* __restrict__ V,
                                                 const ushort* __restrict__ Vt,
                                                 ushort* __restrict__ Ctx) {
    const int qt = blockIdx.x & 7;            // TT/128 = 8 q-tiles
    const int h  = (blockIdx.x >> 3) % HH;
    const int b  = blockIdx.x / (8 * HH);
    const int tid = threadIdx.x;
    const int lane = tid & 63, wave = tid >> 6;
    const int l15 = lane & 15, lq = lane >> 4;

    // 72-element row stride (144B): b128 fragment reads hit the structural
    // bank minimum (a 128B stride would be a 16-way conflict).
    __shared__ __align__(16) ushort Vs [64][72];    // V tile  [t][d]
    __shared__ __align__(16) ushort Vts[64][72];    // V^T tile [d][t]
    __shared__ __align__(16) ushort Ps [128][72];   // P tile  [q][t], wave-private rows

    const int q0 = qt * 128;
    const int wq = wave * 32;

    // Q fragments (32 q rows x 64 d) live in registers for the whole kernel
    bf16x8 qf[2][2];
    const ushort* Qb = Q + ((size_t)(b * TT + q0 + wq)) * DD + h * DH;
#pragma unroll
    for (int i = 0; i < 2; ++i)
#pragma unroll
        for (int ks = 0; ks < 2; ++ks)
            qf[i][ks] = *(const bf16x8*)(Qb + (size_t)(16 * i + l15) * DD + 32 * ks + lq * 8);

    const ushort* Vb  = V  + ((size_t)b * TT) * DD + h * DH;
    const ushort* Vtb = Vt + ((size_t)(b * HH + h) * DH) * TT;

    f32x4 O[2][4];
    float lsum[2][4];
#pragma unroll
    for (int i = 0; i < 2; ++i)
#pragma unroll
        for (int j = 0; j < 4; ++j) O[i][j] = (f32x4){0.f, 0.f, 0.f, 0.f};
#pragma unroll
    for (int i = 0; i < 2; ++i)
#pragma unroll
        for (int r = 0; r < 4; ++r) lsum[i][r] = 0.f;

    // preload tile 0 into registers
    uint4 va[2], vta[2];
#pragma unroll
    for (int c = 0; c < 2; ++c) {
        int idx = tid + 256 * c;
        int row = idx >> 3, q8 = idx & 7;
        va[c]  = *(const uint4*)(Vb  + (size_t)row * DD + q8 * 8);
        vta[c] = *(const uint4*)(Vtb + (size_t)row * TT + q8 * 8);
    }

    for (int t = 0; t < 16; ++t) {
        __syncthreads();                 // previous iter's fragment reads done
#pragma unroll
        for (int c = 0; c < 2; ++c) {
            int idx = tid + 256 * c;
            int row = idx >> 3, q8 = idx & 7;
            *(uint4*)(&Vs[row][q8 * 8])  = va[c];
            *(uint4*)(&Vts[row][q8 * 8]) = vta[c];
        }
        __syncthreads();                 // tiles ready

        // issue next tile's loads now; latency hides under S/exp/PV below
        const int tn = ((t + 1) & 15) * 64;
#pragma unroll
        for (int c = 0; c < 2; ++c) {
            int idx = tid + 256 * c;
            int row = idx >> 3, q8 = idx & 7;
            va[c]  = *(const uint4*)(Vb  + (size_t)(tn + row) * DD + q8 * 8);
            vta[c] = *(const uint4*)(Vtb + (size_t)row * TT + tn + q8 * 8);
        }

        // ---- S = Q . V over d (quirky attention: V plays the key role) ----
        f32x4 s[2][4];
#pragma unroll
        for (int i = 0; i < 2; ++i)
#pragma unroll
            for (int j = 0; j < 4; ++j) s[i][j] = (f32x4){0.f, 0.f, 0.f, 0.f};
#pragma unroll
        for (int ks = 0; ks < 2; ++ks)
#pragma unroll
            for (int j = 0; j < 4; ++j) {
                bf16x8 vf = *(const bf16x8*)(&Vs[16 * j + l15][32 * ks + lq * 8]);
                s[0][j] = __builtin_amdgcn_mfma_f32_16x16x32_bf16(qf[0][ks], vf, s[0][j], 0, 0, 0);
                s[1][j] = __builtin_amdgcn_mfma_f32_16x16x32_bf16(qf[1][ks], vf, s[1][j], 0, 0, 0);
            }

        // ---- P = exp(S*SCALE) rounded to bf16; lsum sums the rounded values
        // so the final normalization matches what PV actually accumulates.
#pragma unroll
        for (int i = 0; i < 2; ++i)
#pragma unroll
            for (int j = 0; j < 4; ++j)
#pragma unroll
                for (int r = 0; r < 4; ++r) {
                    float p = __expf(s[i][j][r] * SCALE);
                    ushort pb = f2b(p);
                    lsum[i][r] += b2f(pb);
                    Ps[wq + 16 * i + lq * 4 + r][16 * j + l15] = pb;
                }
        // wave-private Ps rows: same-wave LDS write->read needs no barrier

        // ---- O += P @ V ----
#pragma unroll
        for (int ks = 0; ks < 2; ++ks) {
            bf16x8 pf0 = *(const bf16x8*)(&Ps[wq + l15][32 * ks + lq * 8]);
            bf16x8 pf1 = *(const bf16x8*)(&Ps[wq + 16 + l15][32 * ks + lq * 8]);
#pragma unroll
            for (int jd = 0; jd < 4; ++jd) {
                bf16x8 vtf = *(const bf16x8*)(&Vts[16 * jd + l15][32 * ks + lq * 8]);
                O[0][jd] = __builtin_amdgcn_mfma_f32_16x16x32_bf16(pf0, vtf, O[0][jd], 0, 0, 0);
                O[1][jd] = __builtin_amdgcn_mfma_f32_16x16x32_bf16(pf1, vtf, O[1][jd], 0, 0, 0);
            }
        }
    }

    // ---- reduce lsum across the 16 lanes sharing the same q rows ----
#pragma unroll
    for (int i = 0; i < 2; ++i)
#pragma unroll
        for (int r = 0; r < 4; ++r) {
            float l = lsum[i][r];
            l += __shfl_xor(l, 1);
            l += __shfl_xor(l, 2);
            l += __shfl_xor(l, 4);
            l += __shfl_xor(l, 8);
            lsum[i][r] = 1.0f / l;
        }

    // ---- normalize + write bf16 ctx ----
    ushort* Cb = Ctx + ((size_t)(b * TT + q0 + wq)) * DD + h * DH;
#pragma unroll
    for (int i = 0; i < 2; ++i)
#pragma unroll
        for (int r = 0; r < 4; ++r) {
            const int row = 16 * i + lq * 4 + r;
            const float inv = lsum[i][r];
#pragma unroll
            for (int jd = 0; jd < 4; ++jd)
                Cb[(size_t)row * DD + 16 * jd + l15] = f2b(O[i][jd][r] * inv);
        }
}

// ---------------------------------------------------------------------------
// Host launch
// ---------------------------------------------------------------------------
extern "C" void kernel_launch(void* const* d_in, const int* in_sizes, int n_in,
                              void* d_out, int out_size, void* d_ws, size_t ws_size,
                              hipStream_t stream) {
    const float* x_in  = (const float*)d_in[0];
    const float* ln1_g = (const float*)d_in[1];
    const float* ln1_b = (const float*)d_in[2];
    const float* Wq    = (const float*)d_in[3];
    const float* bq    = (const float*)d_in[4];
    const float* Wv    = (const float*)d_in[5];
    const float* bv    = (const float*)d_in[6];
    const float* Wo    = (const float*)d_in[7];
    const float* bo    = (const float*)d_in[8];
    const float* ln2_g = (const float*)d_in[9];
    const float* ln2_b = (const float*)d_in[10];
    const float* W1    = (const float*)d_in[11];
    const float* b1    = (const float*)d_in[12];
    const float* W2    = (const float*)d_in[13];
    const float* b2    = (const float*)d_in[14];

    float* x = (float*)d_out;                 // residual stream (fp32)
    ushort* h   = (ushort*)d_ws;              // M*D bf16 (ln1 out; reused as Vt)
    ushort* qb  = h   + (size_t)MM * DD;
    ushort* vb  = qb  + (size_t)MM * DD;
    ushort* ctx = vb  + (size_t)MM * DD;
    ushort* h2  = ctx + (size_t)MM * DD;
    ushort* a1  = h2  + (size_t)MM * DD;      // M*FF bf16
    ushort* Wtq = a1  + (size_t)MM * FF2;
    ushort* Wtv = Wtq + (size_t)DD * DD;
    ushort* Wto = Wtv + (size_t)DD * DD;
    ushort* Wt1 = Wto + (size_t)DD * DD;      // [FF][D]
    ushort* Wt2 = Wt1 + (size_t)DD * FF2;     // [D][FF]
    ushort* vt  = h;   // V^T [(b*H+h)][d][t]; h is dead after the q/v GEMMs

    hipMemcpyAsync(x, x_in, (size_t)MM * DD * sizeof(float),
                   hipMemcpyDeviceToDevice, stream);

    const dim3 blk(256);
    const dim3 t32(32, 8);
    const dim3 gD(12, 32);    // N=768, BN=64
    const dim3 gF(24, 32);    // N=3072, BN=128

    for (int l = 0; l < NL; ++l) {
        const float* Wq_l = Wq + (size_t)l * DD * DD;
        const float* Wv_l = Wv + (size_t)l * DD * DD;
        const float* Wo_l = Wo + (size_t)l * DD * DD;
        const float* W1_l = W1 + (size_t)l * DD * FF2;
        const float* W2_l = W2 + (size_t)l * FF2 * DD;

        tconv<<<dim3(24, 24), t32, 0, stream>>>(Wq_l, Wtq, DD, DD);
        tconv<<<dim3(24, 24), t32, 0, stream>>>(Wv_l, Wtv, DD, DD);
        tconv<<<dim3(24, 24), t32, 0, stream>>>(Wo_l, Wto, DD, DD);
        tconv<<<dim3(96, 24), t32, 0, stream>>>(W1_l, Wt1, DD, FF2);
        tconv<<<dim3(24, 96), t32, 0, stream>>>(W2_l, Wt2, FF2, DD);

        ln_kernel<<<MM, blk, 0, stream>>>(x, ln1_g + l * DD, ln1_b + l * DD, h);

        mfma_gemm<64, 0, true><<<gD, blk, 0, stream>>>(h, Wtq, bq + l * DD, nullptr, qb, MM, DD, DD);
        mfma_gemm<64, 0, true><<<gD, blk, 0, stream>>>(h, Wtv, bv + l * DD, nullptr, vb, MM, DD, DD);

        // V^T for the PV mfma B-operand (aliases h, which is now dead)
        vtrans<<<dim3(TT / 32, DH / 32, BB * HH), t32, 0, stream>>>(vb, vt);

        attn_mfma<<<BB * HH * (TT / 128), blk, 0, stream>>>(qb, vb, vt, ctx);

        // x = x + ctx @ Wo + bo (fp32 residual)
        mfma_gemm<64, 1, false><<<gD, blk, 0, stream>>>(ctx, Wto, bo + l * DD, x, x, MM, DD, DD);

        ln_kernel<<<MM, blk, 0, stream>>>(x, ln2_g + l * DD, ln2_b + l * DD, h2);

        // a1 = gelu(h2 @ W1 + b1)
        mfma_gemm<128, 2, true><<<gF, blk, 0, stream>>>(h2, Wt1, b1 + l * FF2, nullptr, a1, MM, FF2, DD);

        // x = x + a1 @ W2 + b2
        mfma_gemm<64, 1, false><<<gD, blk, 0, stream>>>(a1, Wt2, b2 + l * DD, x, x, MM, DD, FF2);
    }
}